// Round 8
// baseline (31.793 us; speedup 1.0000x reference)
//
#include <hip/hip_runtime.h>
#include <cstdint>
#include <cstddef>

#define MAXG 128

// ---------------- compile-time: reproduce numpy legacy RandomState(42) ----------------
namespace ct {

struct MT19937 {
  uint32_t mt[624] = {};
  int mti = 0;
  constexpr void seed(uint32_t s) {
    mt[0] = s;
    for (int i = 1; i < 624; i++)
      mt[i] = 1812433253u * (mt[i-1] ^ (mt[i-1] >> 30)) + (uint32_t)i;
    mti = 624;
  }
  constexpr uint32_t next() {
    if (mti >= 624) {
      for (int i = 0; i < 624; i++) {
        uint32_t y = (mt[i] & 0x80000000u) | (mt[(i+1) % 624] & 0x7fffffffu);
        mt[i] = mt[(i+397) % 624] ^ (y >> 1) ^ ((y & 1u) ? 2567483615u : 0u);
      }
      mti = 0;
    }
    uint32_t y = mt[mti++];
    y ^= y >> 11; y ^= (y << 7) & 2636928640u; y ^= (y << 15) & 4022730752u; y ^= y >> 18;
    return y;
  }
  constexpr double rdouble() {               // legacy rk_double: two 32-bit draws
    uint32_t a = next() >> 5, b = next() >> 6;
    return ((double)a * 67108864.0 + (double)b) / 9007199254740992.0;
  }
  constexpr uint32_t masked32(uint32_t rng, uint32_t mask) {  // legacy randint
    uint32_t v = next() & mask;
    while (v > rng) v = next() & mask;
    return v;
  }
  constexpr uint32_t interval(uint32_t mx) {  // random_interval (shuffle)
    if (!mx) return 0;
    uint32_t mask = mx;
    mask |= mask >> 1; mask |= mask >> 2; mask |= mask >> 4; mask |= mask >> 8; mask |= mask >> 16;
    uint32_t v = next() & mask;
    while (v > mx) v = next() & mask;
    return v;
  }
};

// gate code: bits[1:0] = kind (0=RX,1=RY,2=RZ,3=CNOT)
//   R:    bits[5:2] = wire bit mask (8>>wire), bits[10:6] = weight index l*8+i
//   CNOT: bits[5:2] = control bit mask,        bits[9:6]  = target bit mask
struct CG { int n = 0; int code[MAXG] = {}; };

constexpr CG build_gates_ct() {
  CG gl{};
  MT19937 rng{};
  rng.seed(42);
  for (int l = 0; l < 4; l++) {
    int i = 0;
    while (i < 8) {
      if (rng.rdouble() > 0.3) {
        int g = (int)rng.masked32(2, 3);   // randint(3)
        int w = (int)rng.masked32(3, 3);   // randint(4)
        int widx = l * 8 + i;
        if (gl.n < MAXG) gl.code[gl.n++] = g | ((8 >> w) << 2) | (widx << 6);
        i++;
      } else {
        int perm[4] = {0, 1, 2, 3};
        for (int ii = 3; ii >= 1; ii--) {
          int j = (int)rng.interval((uint32_t)ii);
          int tmp = perm[ii]; perm[ii] = perm[j]; perm[j] = tmp;
        }
        int cw = perm[0], tw = perm[1];
        if (gl.n < MAXG) gl.code[gl.n++] = 3 | ((8 >> cw) << 2) | ((8 >> tw) << 6);
      }
    }
  }
  return gl;
}

constexpr CG GL = build_gates_ct();

} // namespace ct

// Native trig (validated R7: absmax unchanged). v_sin/v_cos take REVOLUTIONS; our
// half-angles are < pi -> |rev| < 0.5, no range reduction needed.
__device__ __forceinline__ void half_sincos(float a, float& s, float& c) {
  const float r = a * 0.07957747154594767f;   // a * 0.5 / (2*pi)
  s = __builtin_amdgcn_sinf(r);
  c = __builtin_amdgcn_cosf(r);
}

// ---------------- gate chain: template recursion => static indexing GUARANTEED ------
template <int G>
__device__ __forceinline__ void apply_gates(float (&sr)[16], float (&si)[16],
                                            const float* __restrict__ w) {
  if constexpr (G < ct::GL.n) {
    constexpr int code = ct::GL.code[G];
    constexpr int kind = code & 3;
    if constexpr (kind == 3) {              // CNOT: pure register permutation
      constexpr int cbit = (code >> 2) & 15, tbit = (code >> 6) & 15;
      float tr[16], ti[16];
      #pragma unroll
      for (int k = 0; k < 16; k++) {
        const int src = (k & cbit) ? (k ^ tbit) : k;   // all ct-const
        tr[k] = sr[src]; ti[k] = si[src];
      }
      #pragma unroll
      for (int k = 0; k < 16; k++) { sr[k] = tr[k]; si[k] = ti[k]; }
    } else {
      constexpr int bit  = (code >> 2) & 15;
      constexpr int widx = (code >> 6) & 31;
      float sh, ch;
      half_sincos(w[widx], sh, ch);
      float tr[16], ti[16];
      #pragma unroll
      for (int k = 0; k < 16; k++) {
        const int p = k ^ bit;
        if constexpr (kind == 0) {          // RX
          tr[k] = ch * sr[k] + sh * si[p];
          ti[k] = ch * si[k] - sh * sr[p];
        } else if constexpr (kind == 1) {   // RY
          if (k & bit) { tr[k] = ch * sr[k] + sh * sr[p]; ti[k] = ch * si[k] + sh * si[p]; }
          else         { tr[k] = ch * sr[k] - sh * sr[p]; ti[k] = ch * si[k] - sh * si[p]; }
        } else {                            // RZ
          if (k & bit) { tr[k] = ch * sr[k] - sh * si[k]; ti[k] = ch * si[k] + sh * sr[k]; }
          else         { tr[k] = ch * sr[k] + sh * si[k]; ti[k] = ch * si[k] - sh * sr[k]; }
        }
      }
      #pragma unroll
      for (int k = 0; k < 16; k++) { sr[k] = tr[k]; si[k] = ti[k]; }
    }
    apply_gates<G + 1>(sr, si, w);
  }
}

// ---------------- kernel 1: build U, one wave, all-register ----------------
__global__ __launch_bounds__(64) void build_u(const float* __restrict__ w,
                                              float* __restrict__ ws) {
  const int c = threadIdx.x & 15;
  float sr[16], si[16];
  #pragma unroll
  for (int k = 0; k < 16; k++) { sr[k] = (k == c) ? 1.0f : 0.0f; si[k] = 0.0f; }

  apply_gates<0>(sr, si, w);

  if (threadIdx.x < 16) {
    float2* o = (float2*)ws;               // interleaved (re,im), float2 idx = k*16 + col
    #pragma unroll
    for (int k = 0; k < 16; k++) o[k * 16 + c] = make_float2(sr[k], si[k]);
  }
}

// ---------------- U via SMEM: s_load_dwordx16 into SGPRs (wave-uniform operand) -----
// Replaces the 128 broadcast ds_read_b128/thread (LDS pipe was ~10.2us/CU at P=2).
// SMEM runs parallel to VALU/LDS; value broadcasts to all lanes for free; FMA uses
// the SGPR directly (1-SGPR-per-VALU rule ok). The s_waitcnt lives INSIDE the asm
// block that defines the outputs, so consumers cannot be hoisted past it (rule 18).
typedef __attribute__((ext_vector_type(16))) float f32x16;

template <int K>
__device__ __forceinline__ void amp_k(const float* __restrict__ uws,
                                      const float (&s16)[2][16],
                                      float (&acc)[2][4]) {
  if constexpr (K < 16) {
    f32x16 u0, u1;                          // floats K*32 + 0..15 / 16..31
    asm volatile("s_load_dwordx16 %0, %2, %3\n\t"
                 "s_load_dwordx16 %1, %2, %4\n\t"
                 "s_waitcnt lgkmcnt(0)"
                 : "=s"(u0), "=s"(u1)
                 : "s"(uws), "i"(K * 128), "i"(K * 128 + 64));
    // u0[2i]=re(K,i), u0[2i+1]=im(K,i) for i=0..7; u1 likewise for i=8..15
    float ar[2] = {0.f, 0.f}, ai[2] = {0.f, 0.f};
    #pragma unroll
    for (int i = 0; i < 8; i++) {
      #pragma unroll
      for (int p = 0; p < 2; p++) {
        ar[p] += u0[2*i]   * s16[p][i];
        ai[p] += u0[2*i+1] * s16[p][i];
        ar[p] += u1[2*i]   * s16[p][8+i];
        ai[p] += u1[2*i+1] * s16[p][8+i];
      }
    }
    #pragma unroll
    for (int p = 0; p < 2; p++) {
      float pk = ar[p]*ar[p] + ai[p]*ai[p];
      #pragma unroll
      for (int ch = 0; ch < 4; ch++) {
        if constexpr (false) {}
        if (K & (8 >> ch)) acc[p][ch] -= pk; else acc[p][ch] += pk;
      }
    }
    amp_k<K + 1>(uws, s16, acc);
  }
}

// ---------------- kernel 2: R4 structure (P=2, 1024 blocks) + s_load U, no LDS ------
// thread = (b, jj, q), q=0..63; patches kk = q and 64+q; writes its 2 computed f4
// plus 6 zero f4 (right half of its row + mirrored bottom row) -> no memset needed.
__global__ __launch_bounds__(256) void qonv_main(const float* __restrict__ img,
                                                 const float* __restrict__ uws,
                                                 float* __restrict__ out) {
  unsigned tid = blockIdx.x * 256u + (unsigned)threadIdx.x;
  int q  = tid & 63;                       // lane-dense patch index
  int jj = (tid >> 6) & 127;               // patch row
  int b  = tid >> 13;                      // batch

  const float* row0 = img + (size_t)(b * 512 + 2 * jj) * 1536;
  const float* row1 = row0 + 1536;

  const float inv3 = 1.0f / 3.0f;
  float s16[2][16];
  #pragma unroll
  for (int p = 0; p < 2; p++) {
    int off = 384 * p + 6 * q;             // floats; 8B-aligned (even stride)
    float2 x0 = *(const float2*)(row0 + off);
    float2 x1 = *(const float2*)(row0 + off + 2);
    float2 x2 = *(const float2*)(row0 + off + 4);
    float2 y0 = *(const float2*)(row1 + off);
    float2 y1 = *(const float2*)(row1 + off + 2);
    float2 y2 = *(const float2*)(row1 + off + 4);
    float a0 = (x0.x + x0.y + x1.x) * inv3;   // (r0,c0)
    float a1 = (x1.y + x2.x + x2.y) * inv3;   // (r0,c1)
    float a2 = (y0.x + y0.y + y1.x) * inv3;   // (r1,c0)
    float a3 = (y1.y + y2.x + y2.y) * inv3;   // (r1,c1)
    float c0, s0, c1, s1, c2, s2, c3, s3;
    half_sincos(a0, s0, c0);
    half_sincos(a1, s1, c1);
    half_sincos(a2, s2, c2);
    half_sincos(a3, s3, c3);
    float A[4] = {c0*c1, c0*s1, s0*c1, s0*s1};
    float B[4] = {c2*c3, c2*s3, s2*c3, s2*s3};
    #pragma unroll
    for (int hi = 0; hi < 4; hi++)
      #pragma unroll
      for (int lo = 0; lo < 4; lo++)
        s16[p][hi * 4 + lo] = A[hi] * B[lo];
  }

  float acc[2][4];
  #pragma unroll
  for (int p = 0; p < 2; p++)
    #pragma unroll
    for (int c = 0; c < 4; c++) acc[p][c] = 0.0f;

  amp_k<0>(uws, s16, acc);                 // 16 k-rows, U from SGPRs

  float4* o = (float4*)out;                // one float4 = 4 channels of one (b,r,c)
  size_t rowA = ((size_t)b * 256 + jj) * 256;          // computed row
  size_t rowB = ((size_t)b * 256 + 128 + jj) * 256;    // mirrored zero row
  const float4 z4 = make_float4(0.f, 0.f, 0.f, 0.f);
  o[rowA + q]       = make_float4(acc[0][0], acc[0][1], acc[0][2], acc[0][3]);
  o[rowA + 64 + q]  = make_float4(acc[1][0], acc[1][1], acc[1][2], acc[1][3]);
  o[rowA + 128 + q] = z4;
  o[rowA + 192 + q] = z4;
  o[rowB + q]       = z4;
  o[rowB + 64 + q]  = z4;
  o[rowB + 128 + q] = z4;
  o[rowB + 192 + q] = z4;
}

extern "C" void kernel_launch(void* const* d_in, const int* in_sizes, int n_in,
                              void* d_out, int out_size, void* d_ws, size_t ws_size,
                              hipStream_t stream) {
  const float* img = (const float*)d_in[0];
  const float* wts = (const float*)d_in[1];
  float* out = (float*)d_out;

  build_u<<<1, 64, 0, stream>>>(wts, (float*)d_ws);
  qonv_main<<<1024, 256, 0, stream>>>(img, (const float*)d_ws, out);
}

// Round 9
// 23.967 us; speedup vs baseline: 1.3265x; 1.3265x over previous
//
#include <hip/hip_runtime.h>
#include <cstdint>
#include <cstddef>

#define MAXG 128

// ---------------- compile-time: reproduce numpy legacy RandomState(42) ----------------
namespace ct {

struct MT19937 {
  uint32_t mt[624] = {};
  int mti = 0;
  constexpr void seed(uint32_t s) {
    mt[0] = s;
    for (int i = 1; i < 624; i++)
      mt[i] = 1812433253u * (mt[i-1] ^ (mt[i-1] >> 30)) + (uint32_t)i;
    mti = 624;
  }
  constexpr uint32_t next() {
    if (mti >= 624) {
      for (int i = 0; i < 624; i++) {
        uint32_t y = (mt[i] & 0x80000000u) | (mt[(i+1) % 624] & 0x7fffffffu);
        mt[i] = mt[(i+397) % 624] ^ (y >> 1) ^ ((y & 1u) ? 2567483615u : 0u);
      }
      mti = 0;
    }
    uint32_t y = mt[mti++];
    y ^= y >> 11; y ^= (y << 7) & 2636928640u; y ^= (y << 15) & 4022730752u; y ^= y >> 18;
    return y;
  }
  constexpr double rdouble() {               // legacy rk_double: two 32-bit draws
    uint32_t a = next() >> 5, b = next() >> 6;
    return ((double)a * 67108864.0 + (double)b) / 9007199254740992.0;
  }
  constexpr uint32_t masked32(uint32_t rng, uint32_t mask) {  // legacy randint
    uint32_t v = next() & mask;
    while (v > rng) v = next() & mask;
    return v;
  }
  constexpr uint32_t interval(uint32_t mx) {  // random_interval (shuffle)
    if (!mx) return 0;
    uint32_t mask = mx;
    mask |= mask >> 1; mask |= mask >> 2; mask |= mask >> 4; mask |= mask >> 8; mask |= mask >> 16;
    uint32_t v = next() & mask;
    while (v > mx) v = next() & mask;
    return v;
  }
};

// gate code: bits[1:0] = kind (0=RX,1=RY,2=RZ,3=CNOT)
//   R:    bits[5:2] = wire bit mask (8>>wire), bits[10:6] = weight index l*8+i
//   CNOT: bits[5:2] = control bit mask,        bits[9:6]  = target bit mask
struct CG { int n = 0; int code[MAXG] = {}; };

constexpr CG build_gates_ct() {
  CG gl{};
  MT19937 rng{};
  rng.seed(42);
  for (int l = 0; l < 4; l++) {
    int i = 0;
    while (i < 8) {
      if (rng.rdouble() > 0.3) {
        int g = (int)rng.masked32(2, 3);   // randint(3)
        int w = (int)rng.masked32(3, 3);   // randint(4)
        int widx = l * 8 + i;
        if (gl.n < MAXG) gl.code[gl.n++] = g | ((8 >> w) << 2) | (widx << 6);
        i++;
      } else {
        int perm[4] = {0, 1, 2, 3};
        for (int ii = 3; ii >= 1; ii--) {
          int j = (int)rng.interval((uint32_t)ii);
          int tmp = perm[ii]; perm[ii] = perm[j]; perm[j] = tmp;
        }
        int cw = perm[0], tw = perm[1];
        if (gl.n < MAXG) gl.code[gl.n++] = 3 | ((8 >> cw) << 2) | ((8 >> tw) << 6);
      }
    }
  }
  return gl;
}

constexpr CG GL = build_gates_ct();

} // namespace ct

// Native trig (validated R7: absmax unchanged). v_sin/v_cos take REVOLUTIONS; our
// half-angles are < pi -> |rev| < 0.5, no range reduction needed.
__device__ __forceinline__ void half_sincos(float a, float& s, float& c) {
  const float r = a * 0.07957747154594767f;   // a * 0.5 / (2*pi)
  s = __builtin_amdgcn_sinf(r);
  c = __builtin_amdgcn_cosf(r);
}

// ---------------- gate chain: template recursion => static indexing GUARANTEED ------
template <int G>
__device__ __forceinline__ void apply_gates(float (&sr)[16], float (&si)[16],
                                            const float* __restrict__ w) {
  if constexpr (G < ct::GL.n) {
    constexpr int code = ct::GL.code[G];
    constexpr int kind = code & 3;
    if constexpr (kind == 3) {              // CNOT: pure register permutation
      constexpr int cbit = (code >> 2) & 15, tbit = (code >> 6) & 15;
      float tr[16], ti[16];
      #pragma unroll
      for (int k = 0; k < 16; k++) {
        const int src = (k & cbit) ? (k ^ tbit) : k;   // all ct-const
        tr[k] = sr[src]; ti[k] = si[src];
      }
      #pragma unroll
      for (int k = 0; k < 16; k++) { sr[k] = tr[k]; si[k] = ti[k]; }
    } else {
      constexpr int bit  = (code >> 2) & 15;
      constexpr int widx = (code >> 6) & 31;
      float sh, ch;
      half_sincos(w[widx], sh, ch);
      float tr[16], ti[16];
      #pragma unroll
      for (int k = 0; k < 16; k++) {
        const int p = k ^ bit;
        if constexpr (kind == 0) {          // RX
          tr[k] = ch * sr[k] + sh * si[p];
          ti[k] = ch * si[k] - sh * sr[p];
        } else if constexpr (kind == 1) {   // RY
          if (k & bit) { tr[k] = ch * sr[k] + sh * sr[p]; ti[k] = ch * si[k] + sh * si[p]; }
          else         { tr[k] = ch * sr[k] - sh * sr[p]; ti[k] = ch * si[k] - sh * si[p]; }
        } else {                            // RZ
          if (k & bit) { tr[k] = ch * sr[k] - sh * si[k]; ti[k] = ch * si[k] + sh * sr[k]; }
          else         { tr[k] = ch * sr[k] + sh * si[k]; ti[k] = ch * si[k] - sh * sr[k]; }
        }
      }
      #pragma unroll
      for (int k = 0; k < 16; k++) { sr[k] = tr[k]; si[k] = ti[k]; }
    }
    apply_gates<G + 1>(sr, si, w);
  }
}

// ---------------- single fused kernel -----------------------------------------------
// R4 structure (best measured: P=2, 1024 blocks, zero-writes folded in) + per-block
// U rebuild. Lanes 0..15 of wave 0 run the register gate chain (column c of U evolves
// independently as U*e_c) and write 2KB U to LDS; ALL U-independent work (image loads,
// 8 native sincos, s16 outer products, 6 zero-float4 stores) runs before the
// __syncthreads(), hiding the ~1.5us chain. One dispatch: no build_u launch, no
// inter-kernel drain, no d_ws round-trip.
__global__ __launch_bounds__(256) void qonv_fused(const float* __restrict__ img,
                                                  const float* __restrict__ wts,
                                                  float* __restrict__ out) {
  __shared__ float4 U4[128];               // float2 view: [k*16+i] = (Re U[k][i], Im U[k][i])
  const int t = threadIdx.x;

  // ---- U chain (wave 0, lanes 0..15) — issued first so it overlaps patch work below
  if (t < 16) {
    const int c = t;
    float sr[16], si[16];
    #pragma unroll
    for (int k = 0; k < 16; k++) { sr[k] = (k == c) ? 1.0f : 0.0f; si[k] = 0.0f; }
    apply_gates<0>(sr, si, wts);
    float2* uo = (float2*)U4;
    #pragma unroll
    for (int k = 0; k < 16; k++) uo[k * 16 + c] = make_float2(sr[k], si[k]);  // banks 2c,2c+1: conflict-free
  }

  const unsigned tid = blockIdx.x * 256u + (unsigned)t;
  const int q  = tid & 63;                 // lane-dense patch index
  const int jj = (tid >> 6) & 127;         // patch row
  const int b  = tid >> 13;                // batch

  // ---- zero region stores (independent of U): 6 float4 per thread
  float4* o = (float4*)out;
  size_t rowA = ((size_t)b * 256 + jj) * 256;          // computed row
  size_t rowB = ((size_t)b * 256 + 128 + jj) * 256;    // mirrored zero row
  {
    const float4 z4 = make_float4(0.f, 0.f, 0.f, 0.f);
    o[rowA + 128 + q] = z4;
    o[rowA + 192 + q] = z4;
    o[rowB + q]       = z4;
    o[rowB + 64 + q]  = z4;
    o[rowB + 128 + q] = z4;
    o[rowB + 192 + q] = z4;
  }

  // ---- patch means + encoding state (independent of U)
  const float* row0 = img + (size_t)(b * 512 + 2 * jj) * 1536;
  const float* row1 = row0 + 1536;
  const float inv3 = 1.0f / 3.0f;
  float s16[2][16];
  #pragma unroll
  for (int p = 0; p < 2; p++) {
    int off = 384 * p + 6 * q;             // floats; 8B-aligned (even stride)
    float2 x0 = *(const float2*)(row0 + off);
    float2 x1 = *(const float2*)(row0 + off + 2);
    float2 x2 = *(const float2*)(row0 + off + 4);
    float2 y0 = *(const float2*)(row1 + off);
    float2 y1 = *(const float2*)(row1 + off + 2);
    float2 y2 = *(const float2*)(row1 + off + 4);
    float a0 = (x0.x + x0.y + x1.x) * inv3;   // (r0,c0)
    float a1 = (x1.y + x2.x + x2.y) * inv3;   // (r0,c1)
    float a2 = (y0.x + y0.y + y1.x) * inv3;   // (r1,c0)
    float a3 = (y1.y + y2.x + y2.y) * inv3;   // (r1,c1)
    float c0, s0, c1, s1, c2, s2, c3, s3;
    half_sincos(a0, s0, c0);
    half_sincos(a1, s1, c1);
    half_sincos(a2, s2, c2);
    half_sincos(a3, s3, c3);
    float A[4] = {c0*c1, c0*s1, s0*c1, s0*s1};
    float B[4] = {c2*c3, c2*s3, s2*c3, s2*s3};
    #pragma unroll
    for (int hi = 0; hi < 4; hi++)
      #pragma unroll
      for (int lo = 0; lo < 4; lo++)
        s16[p][hi * 4 + lo] = A[hi] * B[lo];
  }

  float acc[2][4];
  #pragma unroll
  for (int p = 0; p < 2; p++)
    #pragma unroll
    for (int c = 0; c < 4; c++) acc[p][c] = 0.0f;

  __syncthreads();                         // U4 ready

  #pragma unroll
  for (int k = 0; k < 16; k++) {
    float ar[2] = {0, 0}, ai[2] = {0, 0};
    #pragma unroll
    for (int i2 = 0; i2 < 8; i2++) {
      float4 u = U4[k * 8 + i2];           // broadcast read, conflict-free
      #pragma unroll
      for (int p = 0; p < 2; p++) {
        ar[p] += u.x * s16[p][2*i2] + u.z * s16[p][2*i2+1];
        ai[p] += u.y * s16[p][2*i2] + u.w * s16[p][2*i2+1];
      }
    }
    #pragma unroll
    for (int p = 0; p < 2; p++) {
      float pk = ar[p]*ar[p] + ai[p]*ai[p];
      #pragma unroll
      for (int ch = 0; ch < 4; ch++) {
        if (k & (8 >> ch)) acc[p][ch] -= pk; else acc[p][ch] += pk;
      }
    }
  }

  o[rowA + q]      = make_float4(acc[0][0], acc[0][1], acc[0][2], acc[0][3]);
  o[rowA + 64 + q] = make_float4(acc[1][0], acc[1][1], acc[1][2], acc[1][3]);
}

extern "C" void kernel_launch(void* const* d_in, const int* in_sizes, int n_in,
                              void* d_out, int out_size, void* d_ws, size_t ws_size,
                              hipStream_t stream) {
  const float* img = (const float*)d_in[0];
  const float* wts = (const float*)d_in[1];
  float* out = (float*)d_out;

  qonv_fused<<<1024, 256, 0, stream>>>(img, wts, out);
}

// Round 11
// 21.014 us; speedup vs baseline: 1.5129x; 1.1405x over previous
//
#include <hip/hip_runtime.h>
#include <cstdint>
#include <cstddef>

#define MAXG 128

// ---------------- compile-time: reproduce numpy legacy RandomState(42) ----------------
namespace ct {

struct MT19937 {
  uint32_t mt[624] = {};
  int mti = 0;
  constexpr void seed(uint32_t s) {
    mt[0] = s;
    for (int i = 1; i < 624; i++)
      mt[i] = 1812433253u * (mt[i-1] ^ (mt[i-1] >> 30)) + (uint32_t)i;
    mti = 624;
  }
  constexpr uint32_t next() {
    if (mti >= 624) {
      for (int i = 0; i < 624; i++) {
        uint32_t y = (mt[i] & 0x80000000u) | (mt[(i+1) % 624] & 0x7fffffffu);
        mt[i] = mt[(i+397) % 624] ^ (y >> 1) ^ ((y & 1u) ? 2567483615u : 0u);
      }
      mti = 0;
    }
    uint32_t y = mt[mti++];
    y ^= y >> 11; y ^= (y << 7) & 2636928640u; y ^= (y << 15) & 4022730752u; y ^= y >> 18;
    return y;
  }
  constexpr double rdouble() {
    uint32_t a = next() >> 5, b = next() >> 6;
    return ((double)a * 67108864.0 + (double)b) / 9007199254740992.0;
  }
  constexpr uint32_t masked32(uint32_t rng, uint32_t mask) {
    uint32_t v = next() & mask;
    while (v > rng) v = next() & mask;
    return v;
  }
  constexpr uint32_t interval(uint32_t mx) {
    if (!mx) return 0;
    uint32_t mask = mx;
    mask |= mask >> 1; mask |= mask >> 2; mask |= mask >> 4; mask |= mask >> 8; mask |= mask >> 16;
    uint32_t v = next() & mask;
    while (v > mx) v = next() & mask;
    return v;
  }
};

struct CG { int n = 0; int code[MAXG] = {}; };

constexpr CG build_gates_ct() {
  CG gl{};
  MT19937 rng{};
  rng.seed(42);
  for (int l = 0; l < 4; l++) {
    int i = 0;
    while (i < 8) {
      if (rng.rdouble() > 0.3) {
        int g = (int)rng.masked32(2, 3);
        int w = (int)rng.masked32(3, 3);
        int widx = l * 8 + i;
        if (gl.n < MAXG) gl.code[gl.n++] = g | ((8 >> w) << 2) | (widx << 6);
        i++;
      } else {
        int perm[4] = {0, 1, 2, 3};
        for (int ii = 3; ii >= 1; ii--) {
          int j = (int)rng.interval((uint32_t)ii);
          int tmp = perm[ii]; perm[ii] = perm[j]; perm[j] = tmp;
        }
        int cw = perm[0], tw = perm[1];
        if (gl.n < MAXG) gl.code[gl.n++] = 3 | ((8 >> cw) << 2) | ((8 >> tw) << 6);
      }
    }
  }
  return gl;
}

constexpr CG GL = build_gates_ct();

} // namespace ct

typedef __attribute__((ext_vector_type(8))) short short8;   // 8 bf16 (4 VGPR) MFMA frag
typedef __attribute__((ext_vector_type(4))) float f32x4;    // 16x16 accumulator

// Native trig (validated R7: absmax unchanged). Inputs in revolutions; |rev|<0.5.
__device__ __forceinline__ void half_sincos(float a, float& s, float& c) {
  const float r = a * 0.07957747154594767f;   // a * 0.5 / (2*pi)
  s = __builtin_amdgcn_sinf(r);
  c = __builtin_amdgcn_cosf(r);
}

// bf16 split helpers (truncation; lo-term absorbs hi rounding, net err ~2^-16)
__device__ __forceinline__ float hi_part(float a) {
  return __uint_as_float(__float_as_uint(a) & 0xffff0000u);
}
__device__ __forceinline__ unsigned pack_hi(float a, float b) {   // low short = a's bf16
  return (__float_as_uint(a) >> 16) | (__float_as_uint(b) & 0xffff0000u);
}
__device__ __forceinline__ short8 pack8(float v0, float v1, float v2, float v3,
                                        float v4, float v5, float v6, float v7) {
  union { unsigned u[4]; short8 s; } r;
  r.u[0] = pack_hi(v0, v1); r.u[1] = pack_hi(v2, v3);
  r.u[2] = pack_hi(v4, v5); r.u[3] = pack_hi(v6, v7);
  return r.s;
}

// ---------------- gate chain: template recursion => static indexing GUARANTEED ------
template <int G>
__device__ __forceinline__ void apply_gates(float (&sr)[16], float (&si)[16],
                                            const float* __restrict__ w) {
  if constexpr (G < ct::GL.n) {
    constexpr int code = ct::GL.code[G];
    constexpr int kind = code & 3;
    if constexpr (kind == 3) {              // CNOT: register permutation
      constexpr int cbit = (code >> 2) & 15, tbit = (code >> 6) & 15;
      float tr[16], ti[16];
      #pragma unroll
      for (int k = 0; k < 16; k++) {
        const int src = (k & cbit) ? (k ^ tbit) : k;
        tr[k] = sr[src]; ti[k] = si[src];
      }
      #pragma unroll
      for (int k = 0; k < 16; k++) { sr[k] = tr[k]; si[k] = ti[k]; }
    } else {
      constexpr int bit  = (code >> 2) & 15;
      constexpr int widx = (code >> 6) & 31;
      float sh, ch;
      half_sincos(w[widx], sh, ch);
      float tr[16], ti[16];
      #pragma unroll
      for (int k = 0; k < 16; k++) {
        const int p = k ^ bit;
        if constexpr (kind == 0) {          // RX
          tr[k] = ch * sr[k] + sh * si[p];
          ti[k] = ch * si[k] - sh * sr[p];
        } else if constexpr (kind == 1) {   // RY
          if (k & bit) { tr[k] = ch * sr[k] + sh * sr[p]; ti[k] = ch * si[k] + sh * si[p]; }
          else         { tr[k] = ch * sr[k] - sh * sr[p]; ti[k] = ch * si[k] - sh * si[p]; }
        } else {                            // RZ
          if (k & bit) { tr[k] = ch * sr[k] - sh * si[k]; ti[k] = ch * si[k] + sh * sr[k]; }
          else         { tr[k] = ch * sr[k] + sh * si[k]; ti[k] = ch * si[k] - sh * sr[k]; }
        }
      }
      #pragma unroll
      for (int k = 0; k < 16; k++) { sr[k] = tr[k]; si[k] = ti[k]; }
    }
    apply_gates<G + 1>(sr, si, w);
  }
}

// ---------------- kernel 1: build U + emit 16x16x32 A-fragments ----------------------
// K=32 semantic: kk<16 -> s_hi slot i=kk; kk>=16 -> s_lo slot i=kk-16.
// A1 = [U_hi | U_hi] (catches U_hi*s_hi + U_hi*s_lo), A2 = [U_lo | 0] (U_lo*s_hi).
// Fragment (our chosen relabel, same for A and B): lane l -> row=l&15, elems j=0..7
// hold kk = 8*(l>>4)+j.  ws: [0]=Are1 [64]=Are2 [128]=Aim1 [192]=Aim2 (short8 idx).
__global__ __launch_bounds__(64) void build_u(const float* __restrict__ w,
                                              float* __restrict__ ws) {
  __shared__ float2 Ul[256];               // [k*16 + i] = (Re U[k][i], Im U[k][i])
  const int l = threadIdx.x;
  const int c = l & 15;
  float sr[16], si[16];
  #pragma unroll
  for (int k = 0; k < 16; k++) { sr[k] = (k == c) ? 1.0f : 0.0f; si[k] = 0.0f; }
  apply_gates<0>(sr, si, w);
  if (l < 16) {
    #pragma unroll
    for (int k = 0; k < 16; k++) Ul[k * 16 + c] = make_float2(sr[k], si[k]);
  }
  __syncthreads();

  const int row = l & 15, g = l >> 4;
  float re1[8], re2[8], im1[8], im2[8];
  #pragma unroll
  for (int j = 0; j < 8; j++) {
    const int kk = 8 * g + j;
    const int i = kk & 15;
    float2 u = Ul[row * 16 + i];
    float reh = hi_part(u.x), rel = u.x - reh;
    float imh = hi_part(u.y), iml = u.y - imh;
    re1[j] = reh;
    im1[j] = imh;
    re2[j] = (kk < 16) ? rel : 0.f;
    im2[j] = (kk < 16) ? iml : 0.f;
  }
  short8* o = (short8*)ws;
  o[l]       = pack8(re1[0],re1[1],re1[2],re1[3],re1[4],re1[5],re1[6],re1[7]);
  o[64 + l]  = pack8(re2[0],re2[1],re2[2],re2[3],re2[4],re2[5],re2[6],re2[7]);
  o[128 + l] = pack8(im1[0],im1[1],im1[2],im1[3],im1[4],im1[5],im1[6],im1[7]);
  o[192 + l] = pack8(im2[0],im2[1],im2[2],im2[3],im2[4],im2[5],im2[6],im2[7]);
}

// ---------------- per-tile epilogue: layout-proof re/im pairing -----------------------
// acc_re[e], acc_im[e] share (row,col) by construction. Signs use the m89-verified
// k = 4*(lane>>4)+e: ch0 sign (k&8) = g&2, ch1 (k&4) = g&1 (lane-const); ch2 (k&2)=e&2,
// ch3 (k&1)=e&1. Reduce over the 4 row-groups via xor16+xor32.
__device__ __forceinline__ float4 tile_epi(const f32x4& ar, const f32x4& ai, int g) {
  float pk0 = ar[0]*ar[0] + ai[0]*ai[0];
  float pk1 = ar[1]*ar[1] + ai[1]*ai[1];
  float pk2 = ar[2]*ar[2] + ai[2]*ai[2];
  float pk3 = ar[3]*ar[3] + ai[3]*ai[3];
  float s  = (pk0 + pk1) + (pk2 + pk3);
  float p0 = (g & 2) ? -s : s;
  float p1 = (g & 1) ? -s : s;
  float p2 = (pk0 + pk1) - (pk2 + pk3);
  float p3 = (pk0 - pk1) + (pk2 - pk3);
  p0 += __shfl_xor(p0, 16); p0 += __shfl_xor(p0, 32);
  p1 += __shfl_xor(p1, 16); p1 += __shfl_xor(p1, 32);
  p2 += __shfl_xor(p2, 16); p2 += __shfl_xor(p2, 32);
  p3 += __shfl_xor(p3, 16); p3 += __shfl_xor(p3, 32);
  return make_float4(p0, p1, p2, p3);
}

// ---------------- kernel 2: MFMA qonv, 16x16x32, wave = 64 patches -------------------
// 2048 blocks x 256 thr. Per wave: each lane encodes 1 patch, stages [sh(16);sl(16)]
// bf16 to wave-private LDS ([patch][32 shorts]); 4 tiles of 16 patches, each 4 MFMAs
// (re,im x A1,A2). Store: lane l -> patch kkb+l (res of tile l>>4, col l&15).
__global__ __launch_bounds__(256) void qonv_mfma(const float* __restrict__ img,
                                                 const float* __restrict__ uws,
                                                 float* __restrict__ out) {
  __shared__ short slds[4][2048];          // per wave 4KB
  const int t = threadIdx.x;
  const int lane = t & 63, w = t >> 6;
  const int c16 = lane & 15, g = lane >> 4;

  const short8* A8 = (const short8*)uws;
  const short8 Ar1 = A8[lane], Ar2 = A8[64 + lane];
  const short8 Ai1 = A8[128 + lane], Ai2 = A8[192 + lane];

  const unsigned W = blockIdx.x * 4u + (unsigned)w;
  const int b = W >> 8, jj = (W >> 1) & 127, kkb = (W & 1) * 64;
  const int kk = kkb + lane;

  // ---- zero region: 3 grid-strided f4 per thread (validated decode, R7/R9)
  {
    const unsigned PERB = 49152u;
    float4* o4 = (float4*)out;
    const float4 z = make_float4(0.f, 0.f, 0.f, 0.f);
    unsigned tid = blockIdx.x * 256u + (unsigned)t;
    #pragma unroll
    for (int it = 0; it < 3; it++) {
      unsigned zi = tid + (unsigned)it * 524288u;
      unsigned bb = zi / PERB;
      unsigned r = zi - bb * PERB;
      unsigned row, col;
      if (r < 16384u) { row = r >> 7;               col = 128u + (r & 127u); }
      else            { unsigned r2 = r - 16384u;   row = 128u + (r2 >> 8); col = r2 & 255u; }
      o4[((size_t)bb * 256u + row) * 256u + col] = z;
    }
  }

  // ---- encoding: one patch per lane (validated math)
  const float* row0 = img + (size_t)(b * 512 + 2 * jj) * 1536 + 6 * kk;
  const float* row1 = row0 + 1536;
  const float inv3 = 1.0f / 3.0f;
  float2 x0 = *(const float2*)(row0);
  float2 x1 = *(const float2*)(row0 + 2);
  float2 x2 = *(const float2*)(row0 + 4);
  float2 y0 = *(const float2*)(row1);
  float2 y1 = *(const float2*)(row1 + 2);
  float2 y2 = *(const float2*)(row1 + 4);
  float a0 = (x0.x + x0.y + x1.x) * inv3;
  float a1 = (x1.y + x2.x + x2.y) * inv3;
  float a2 = (y0.x + y0.y + y1.x) * inv3;
  float a3 = (y1.y + y2.x + y2.y) * inv3;
  float c0, s0, c1, s1, c2, s2, c3, s3;
  half_sincos(a0, s0, c0);
  half_sincos(a1, s1, c1);
  half_sincos(a2, s2, c2);
  half_sincos(a3, s3, c3);
  float A4[4] = {c0 * c1, c0 * s1, s0 * c1, s0 * s1};
  float B4[4] = {c2 * c3, c2 * s3, s2 * c3, s2 * s3};
  float s16[16];
  #pragma unroll
  for (int hi = 0; hi < 4; hi++)
    #pragma unroll
    for (int lo = 0; lo < 4; lo++)
      s16[hi * 4 + lo] = A4[hi] * B4[lo];

  float sh_[16], sl_[16];
  #pragma unroll
  for (int i = 0; i < 16; i++) {
    float hv = hi_part(s16[i]);
    sh_[i] = hv; sl_[i] = s16[i] - hv;
  }

  // ---- stage: patch=lane holds 32 shorts = [sh(16); sl(16)]
  short* wb = &slds[w][0];
  *(short8*)(wb + lane * 32 +  0) = pack8(sh_[0],sh_[1],sh_[2],sh_[3],sh_[4],sh_[5],sh_[6],sh_[7]);
  *(short8*)(wb + lane * 32 +  8) = pack8(sh_[8],sh_[9],sh_[10],sh_[11],sh_[12],sh_[13],sh_[14],sh_[15]);
  *(short8*)(wb + lane * 32 + 16) = pack8(sl_[0],sl_[1],sl_[2],sl_[3],sl_[4],sl_[5],sl_[6],sl_[7]);
  *(short8*)(wb + lane * 32 + 24) = pack8(sl_[8],sl_[9],sl_[10],sl_[11],sl_[12],sl_[13],sl_[14],sl_[15]);

  // ---- 4 tiles of 16 patches; B-frag: elems j -> kk=8g+j of patch (16*tile + c16)
  f32x4 zf = {0.f, 0.f, 0.f, 0.f};
  float4 res0, res1, res2, res3;
  {
    short8 B = *(const short8*)(wb + (0 * 16 + c16) * 32 + 8 * g);
    f32x4 ar = zf, ai = zf;
    ar = __builtin_amdgcn_mfma_f32_16x16x32_bf16(Ar1, B, ar, 0, 0, 0);
    ar = __builtin_amdgcn_mfma_f32_16x16x32_bf16(Ar2, B, ar, 0, 0, 0);
    ai = __builtin_amdgcn_mfma_f32_16x16x32_bf16(Ai1, B, ai, 0, 0, 0);
    ai = __builtin_amdgcn_mfma_f32_16x16x32_bf16(Ai2, B, ai, 0, 0, 0);
    res0 = tile_epi(ar, ai, g);
  }
  {
    short8 B = *(const short8*)(wb + (1 * 16 + c16) * 32 + 8 * g);
    f32x4 ar = zf, ai = zf;
    ar = __builtin_amdgcn_mfma_f32_16x16x32_bf16(Ar1, B, ar, 0, 0, 0);
    ar = __builtin_amdgcn_mfma_f32_16x16x32_bf16(Ar2, B, ar, 0, 0, 0);
    ai = __builtin_amdgcn_mfma_f32_16x16x32_bf16(Ai1, B, ai, 0, 0, 0);
    ai = __builtin_amdgcn_mfma_f32_16x16x32_bf16(Ai2, B, ai, 0, 0, 0);
    res1 = tile_epi(ar, ai, g);
  }
  {
    short8 B = *(const short8*)(wb + (2 * 16 + c16) * 32 + 8 * g);
    f32x4 ar = zf, ai = zf;
    ar = __builtin_amdgcn_mfma_f32_16x16x32_bf16(Ar1, B, ar, 0, 0, 0);
    ar = __builtin_amdgcn_mfma_f32_16x16x32_bf16(Ar2, B, ar, 0, 0, 0);
    ai = __builtin_amdgcn_mfma_f32_16x16x32_bf16(Ai1, B, ai, 0, 0, 0);
    ai = __builtin_amdgcn_mfma_f32_16x16x32_bf16(Ai2, B, ai, 0, 0, 0);
    res2 = tile_epi(ar, ai, g);
  }
  {
    short8 B = *(const short8*)(wb + (3 * 16 + c16) * 32 + 8 * g);
    f32x4 ar = zf, ai = zf;
    ar = __builtin_amdgcn_mfma_f32_16x16x32_bf16(Ar1, B, ar, 0, 0, 0);
    ar = __builtin_amdgcn_mfma_f32_16x16x32_bf16(Ar2, B, ar, 0, 0, 0);
    ai = __builtin_amdgcn_mfma_f32_16x16x32_bf16(Ai1, B, ai, 0, 0, 0);
    ai = __builtin_amdgcn_mfma_f32_16x16x32_bf16(Ai2, B, ai, 0, 0, 0);
    res3 = tile_epi(ar, ai, g);
  }

  // ---- store: lane l owns patch kkb + l = kkb + 16*(l>>4) + (l&15) -> res[g], col c16
  float4 rA = (g & 1) ? res1 : res0;
  float4 rB = (g & 1) ? res3 : res2;
  float4 mine = (g & 2) ? rB : rA;
  ((float4*)out)[((size_t)b * 256 + jj) * 256 + kkb + lane] = mine;
}

extern "C" void kernel_launch(void* const* d_in, const int* in_sizes, int n_in,
                              void* d_out, int out_size, void* d_ws, size_t ws_size,
                              hipStream_t stream) {
  const float* img = (const float*)d_in[0];
  const float* wts = (const float*)d_in[1];
  float* out = (float*)d_out;

  build_u<<<1, 64, 0, stream>>>(wts, (float*)d_ws);
  qonv_mfma<<<2048, 256, 0, stream>>>(img, (const float*)d_ws, out);
}